// Round 14
// baseline (126.377 us; speedup 1.0000x reference)
//
#include <hip/hip_runtime.h>
#include <hip/hip_bf16.h>

typedef __bf16 bf16x8 __attribute__((ext_vector_type(8)));
typedef float  f32x4  __attribute__((ext_vector_type(4)));

#define MFMA16(a,b,c) __builtin_amdgcn_mfma_f32_16x16x32_bf16((a),(b),(c),0,0,0)

__device__ __forceinline__ unsigned short f2bf(float f){
  unsigned int u = __float_as_uint(f);
  u += 0x7fffu + ((u >> 16) & 1u);
  return (unsigned short)(u >> 16);
}

// pack 2 f32 -> 2 bf16 in one instr (RTE)
__device__ __forceinline__ unsigned int cvtpk(float lo, float hi){
  unsigned int r;
  asm("v_cvt_pk_bf16_f32 %0, %1, %2" : "=v"(r) : "v"(lo), "v"(hi));
  return r;
}

// LDS-visibility sync WITHOUT vmcnt(0) drain (keeps global loads in flight)
__device__ __forceinline__ void block_sync(){
  asm volatile("s_waitcnt lgkmcnt(0)" ::: "memory");
  __builtin_amdgcn_s_barrier();
}

constexpr float SCALE_LOG2E = 0.125f * 1.4426950408889634f; // 1/sqrt(64) * log2(e)

// ---------------- merged prep kernel ----------------
// blocks 0..31: qs + AqT fragments ; 32..287: Cmat+cvec ; 288..543: starts scan
__global__ void k_prep(const float* __restrict__ queries, const float* __restrict__ ipw,
                       const float* __restrict__ ipb, const float* __restrict__ opw,
                       const float* __restrict__ opb, const int* __restrict__ batch,
                       int total, int* __restrict__ starts,
                       unsigned short* __restrict__ AqF,
                       unsigned short* __restrict__ Cmat, float* __restrict__ cvec)
{
  __shared__ __align__(16) float sh[256];
  __shared__ __align__(16) float sh2[256];
  const int t = threadIdx.x, bid = blockIdx.x;

  if (bid < 32){
    const int q = bid;
    sh[t] = queries[q*256 + t];
    __syncthreads();
    const float* wr = ipw + (size_t)t*256;
    float acc = 0.f;
    #pragma unroll 8
    for (int j = 0; j < 256; j += 4){
      float4 wv = *reinterpret_cast<const float4*>(wr + j);
      float4 qv = *reinterpret_cast<const float4*>(&sh[j]);
      acc += wv.x*qv.x + wv.y*qv.y + wv.z*qv.z + wv.w*qv.w;
    }
    sh2[t] = acc + ipb[t];
    __syncthreads();
    #pragma unroll
    for (int h = 0; h < 4; h++){
      const float* wk = ipw + (size_t)(256 + h*64)*256 + t;
      float a2 = 0.f;
      #pragma unroll 8
      for (int d = 0; d < 64; d++) a2 += sh2[h*64 + d] * wk[(size_t)d*256];
      // B-frag layout: AqF[rg=h*2+qh][kb=f>>5][lane=((f>>3)&3)*16 + (q&15)][j=f&7]
      const int dst = ((h*2 + (q>>4))*8 + (t>>5))*512 + (((t>>3)&3)*16 + (q&15))*8 + (t&7);
      AqF[dst] = f2bf(a2 * SCALE_LOG2E);
    }
  } else if (bid < 288){
    const int g = bid - 32;
    sh[t] = opw[(size_t)g*256 + t];
    __syncthreads();
    #pragma unroll
    for (int h = 0; h < 4; h++){
      const float* wv = ipw + (size_t)(512 + h*64)*256 + t;
      float acc = 0.f;
      #pragma unroll 8
      for (int d = 0; d < 64; d++) acc += wv[(size_t)d*256] * sh[h*64 + d];
      Cmat[(size_t)g*1024 + h*256 + t] = f2bf(acc);
    }
    sh2[t] = ipb[512 + t] * sh[t];
    __syncthreads();
    for (int off = 128; off > 0; off >>= 1){
      if (t < off) sh2[t] += sh2[t + off];
      __syncthreads();
    }
    if (t == 0) cvec[g] = sh2[0] + opb[g];
  } else {
    const int sb = bid - 288;
    const int i0 = sb*1024 + t*4;
    if (i0 + 3 < total){
      if (i0 == 0) starts[0] = 0;
      const int4 b4 = *reinterpret_cast<const int4*>(batch + i0);
      if (b4.y != b4.x) starts[b4.y] = i0 + 1;
      if (b4.z != b4.y) starts[b4.z] = i0 + 2;
      if (b4.w != b4.z) starts[b4.w] = i0 + 3;
      if (i0 + 4 < total){
        const int nxt = batch[i0 + 4];
        if (nxt != b4.w) starts[nxt] = i0 + 4;
      } else {
        starts[128] = total;
      }
    }
  }
}

// ---------------- fused attention over raw x (no-max softmax) ----------------
// grid 256 = graph*2 splits, 1024 threads (16 waves, 4 waves/SIMD).
// r13 structure + (1) 2-interval-deep register load pipeline (rA/rB: loads for
// chunk c+3 issued in interval c, consumed in interval c+2 -> vmcnt never blocks)
// + (2) PV bv(c) prefetched at top of interval c (xT[cur3] complete since B_c).

#define LOADC(dst, c_) { \
  const int c0_ = (c_)*32; \
  _Pragma("unroll") \
  for (int n = 0; n < 2; n++){ \
    int nl_ = c0_ + np*2 + n; nl_ = nl_ < cnt-1 ? nl_ : cnt-1; \
    dst[n] = *reinterpret_cast<const float4*>(xg + (size_t)nl_*256 + fq*4); } }

// xsub [node][f] pad 264 ; xT [f][node] pad 40 + XOR swizzle
#define STAGE(xsP, xtP, src) { \
  _Pragma("unroll") \
  for (int n = 0; n < 2; n++){ \
    uint2 w_; w_.x = cvtpk(src[n].x, src[n].y); w_.y = cvtpk(src[n].z, src[n].w); \
    *reinterpret_cast<uint2*>(&(xsP)[(np*2 + n)*264 + fq*4]) = w_; \
  } \
  { const int fb_ = fq*4; \
    const unsigned int wx = cvtpk(src[0].x, src[1].x); \
    const unsigned int wy = cvtpk(src[0].y, src[1].y); \
    const unsigned int wz = cvtpk(src[0].z, src[1].z); \
    const unsigned int ww = cvtpk(src[0].w, src[1].w); \
    char* xb_ = reinterpret_cast<char*>(xtP); \
    *reinterpret_cast<unsigned int*>(xb_ + (((fb_+0)*80 + np*4) ^ ((((fb_+0)>>2)&7)<<4))) = wx; \
    *reinterpret_cast<unsigned int*>(xb_ + (((fb_+1)*80 + np*4) ^ ((((fb_+1)>>2)&7)<<4))) = wy; \
    *reinterpret_cast<unsigned int*>(xb_ + (((fb_+2)*80 + np*4) ^ ((((fb_+2)>>2)&7)<<4))) = wz; \
    *reinterpret_cast<unsigned int*>(xb_ + (((fb_+3)*80 + np*4) ^ ((((fb_+3)>>2)&7)<<4))) = ww; \
  } }

// stage chunk c+1 from parity reg, refill that reg with chunk c+3
#define STAGE_NEXT(xsP, xtP, c_) { \
  if (((c_) + 1) & 1){ STAGE(xsP, xtP, rB); if ((c_) + 3 < chunks) LOADC(rB, (c_) + 3); } \
  else               { STAGE(xsP, xtP, rA); if ((c_) + 3 < chunks) LOADC(rA, (c_) + 3); } }

__global__ __launch_bounds__(1024, 4) void k_attn(
    const float* __restrict__ x, const int* __restrict__ starts,
    const unsigned short* __restrict__ AqF,
    unsigned short* __restrict__ partO, float* __restrict__ partL)
{
  __shared__ __align__(16) unsigned short xsub[2][32*264];
  __shared__ __align__(16) unsigned short xT  [3][256*40];
  __shared__ __align__(16) unsigned short Plds[2][128*40];
  __shared__ __align__(16) float lred[2][128];

  const int tid = threadIdx.x;
  const int wave = tid >> 6, lane = tid & 63, lg = lane >> 4, li = lane & 15;
  const int np = wave, fq = lane;              // stage role: 2 nodes per wave, f-quad per lane
  const int bid = blockIdx.x;
  const int g = bid >> 1, s = bid & 1;
  const int s0 = starts[g], s1 = starts[g+1];
  const int cntg = s1 - s0;
  const int half = (cntg + 1) >> 1;
  const int nstart = s0 + s*half;
  int cnt = cntg - s*half; cnt = cnt < 0 ? 0 : (cnt > half ? half : cnt);
  const int chunks = (cnt + 31) >> 5;
  const float* xg = x + (size_t)nstart*256;
  const int pbase = bid*128;

  float4 rA[2], rB[2];
  if (chunks > 0){
    LOADC(rA, 0);
    if (chunks > 1) LOADC(rB, 1);
    STAGE(xsub[0], xT[0], rA);
    if (chunks > 2) LOADC(rA, 2);
  }
  block_sync();   // B0

  // PV tile bases (used in epilogue too)
  const int pw = wave - 8;
  const int rbase = (pw & 1) * 64;
  const int fbase = (pw >> 1) * 64;
  f32x4 oacc[4][4];  // PV accumulators
  #pragma unroll
  for (int i = 0; i < 4; i++)
    #pragma unroll
    for (int j = 0; j < 4; j++) oacc[i][j] = f32x4{0.f,0.f,0.f,0.f};

  if (wave < 8){
    // ================= S-waves =================
    const int rg2 = wave >> 1, bsel = wave & 1;
    bf16x8 bfragS[2][8];
    #pragma unroll
    for (int rf = 0; rf < 2; rf++)
      #pragma unroll
      for (int kb = 0; kb < 8; kb++)
        bfragS[rf][kb] = *reinterpret_cast<const bf16x8*>(AqF + (size_t)((rg2*2 + rf)*8 + kb)*512 + lane*8);

    float rsum0 = 0.f, rsum1 = 0.f;
    const int row0 = rg2*32 + li, row1 = rg2*32 + 16 + li;
    const int pbyte0 = (row0*80 + bsel*32 + lg*8) ^ (((row0>>2)&7)<<4);
    const int pbyte1 = (row1*80 + bsel*32 + lg*8) ^ (((row1>>2)&7)<<4);

    int wr3 = 1;
    for (int c = 0; c < chunks; ++c){
      const int cur2 = c & 1;

      // ---- S(c): batched fragment reads + 16 MFMA ----
      f32x4 sc0 = f32x4{0.f,0.f,0.f,0.f}, sc1 = f32x4{0.f,0.f,0.f,0.f};
      const unsigned short* xs = &xsub[cur2][(bsel*16 + li)*264 + lg*8];
      bf16x8 af[4];
      __builtin_amdgcn_s_setprio(1);
      #pragma unroll
      for (int kb = 0; kb < 4; kb++) af[kb] = *reinterpret_cast<const bf16x8*>(xs + kb*32);
      #pragma unroll
      for (int kb = 0; kb < 4; kb++){
        sc0 = MFMA16(af[kb], bfragS[0][kb], sc0);
        sc1 = MFMA16(af[kb], bfragS[1][kb], sc1);
      }
      #pragma unroll
      for (int kb = 0; kb < 4; kb++) af[kb] = *reinterpret_cast<const bf16x8*>(xs + (4+kb)*32);
      #pragma unroll
      for (int kb = 0; kb < 4; kb++){
        sc0 = MFMA16(af[kb], bfragS[0][4+kb], sc0);
        sc1 = MFMA16(af[kb], bfragS[1][4+kb], sc1);
      }
      __builtin_amdgcn_s_setprio(0);

      // ---- stage chunk c+1 (overlaps exp2 chain); refill parity reg with c+3 ----
      if (c + 1 < chunks){
        STAGE_NEXT(xsub[(c + 1) & 1], xT[wr3], c);
      }

      // ---- P = exp2(S), masked; P-write ----
      const int nodebase = c*32 + bsel*16 + lg*4;
      float p0[4], p1[4];
      #pragma unroll
      for (int r = 0; r < 4; r++){
        const bool v = (nodebase + r) < cnt;
        p0[r] = v ? __builtin_exp2f(sc0[r]) : 0.f;
        p1[r] = v ? __builtin_exp2f(sc1[r]) : 0.f;
        rsum0 += p0[r]; rsum1 += p1[r];
      }
      {
        char* pl = reinterpret_cast<char*>(Plds[cur2]);
        uint2 w0; w0.x = cvtpk(p0[0], p0[1]); w0.y = cvtpk(p0[2], p0[3]);
        uint2 w1; w1.x = cvtpk(p1[0], p1[1]); w1.y = cvtpk(p1[2], p1[3]);
        *reinterpret_cast<uint2*>(pl + pbyte0) = w0;
        *reinterpret_cast<uint2*>(pl + pbyte1) = w1;
      }

      block_sync();   // B_{c+1}
      wr3 = (wr3 == 2) ? 0 : wr3 + 1;
    }

    rsum0 += __shfl_xor(rsum0, 16); rsum0 += __shfl_xor(rsum0, 32);
    rsum1 += __shfl_xor(rsum1, 16); rsum1 += __shfl_xor(rsum1, 32);
    if (lane < 16){
      lred[bsel][rg2*32 + li]      = rsum0;
      lred[bsel][rg2*32 + 16 + li] = rsum1;
    }
  } else {
    // ================= PV-waves =================
    int bvb[4], pab[4];
    #pragma unroll
    for (int t4 = 0; t4 < 4; t4++){
      const int fr = fbase + t4*16 + li;
      bvb[t4] = (fr*80 + lg*16) ^ (((fr>>2)&7)<<4);
      const int pr = rbase + t4*16 + li;
      pab[t4] = (pr*80 + lg*16) ^ (((pr>>2)&7)<<4);
    }

    int cur3 = 0;
    for (int c = 0; c < chunks; ++c){
      const int cur2 = c & 1;
      const int nxt3 = (cur3 == 2) ? 0 : cur3 + 1;

      // ---- bv(c) prefetch: xT[cur3] complete since B_c ----
      const char* xtC = reinterpret_cast<const char*>(xT[cur3]);
      bf16x8 bv[4];
      #pragma unroll
      for (int ft = 0; ft < 4; ft++)
        bv[ft] = *reinterpret_cast<const bf16x8*>(xtC + bvb[ft]);

      // ---- stage chunk c+1; refill parity reg with c+3 ----
      if (c + 1 < chunks){
        STAGE_NEXT(xsub[(c + 1) & 1], xT[nxt3], c);
      }
      block_sync();   // B_{c+1}

      // ---- PV(c): pa batch, then pure MFMA cluster ----
      const char* plC = reinterpret_cast<const char*>(Plds[cur2]);
      bf16x8 pa[4];
      #pragma unroll
      for (int rt = 0; rt < 4; rt++)
        pa[rt] = *reinterpret_cast<const bf16x8*>(plC + pab[rt]);
      __builtin_amdgcn_s_setprio(1);
      #pragma unroll
      for (int rt = 0; rt < 4; rt++){
        #pragma unroll
        for (int ft = 0; ft < 4; ft++)
          oacc[rt][ft] = MFMA16(pa[rt], bv[ft], oacc[rt][ft]);
      }
      __builtin_amdgcn_s_setprio(0);
      cur3 = nxt3;
    }
  }

  block_sync();   // final: lred visible to all waves

  if (wave >= 8){
    // ---- epilogue: normalize by this block's L_s and store bf16 ----
    #pragma unroll
    for (int rt = 0; rt < 4; rt++){
      const int r0 = rbase + rt*16 + lg*4;
      const f32x4 L0v = *reinterpret_cast<const f32x4*>(&lred[0][r0]);
      const f32x4 L1v = *reinterpret_cast<const f32x4*>(&lred[1][r0]);
      #pragma unroll
      for (int r = 0; r < 4; r++){
        const float L = L0v[r] + L1v[r];
        const float inv = (L > 0.f) ? 1.f/L : 0.f;
        const size_t orow = (size_t)(pbase + r0 + r)*256;
        #pragma unroll
        for (int ft = 0; ft < 4; ft++)
          partO[orow + fbase + ft*16 + li] = f2bf(oacc[rt][ft][r]*inv);
      }
    }
  }
  if (tid < 128) partL[pbase + tid] = lred[0][tid] + lred[1][tid];
}

// ---------------- combine normalized partials + out-proj GEMM ----------------
__global__ __launch_bounds__(512, 1) void k_out(
    const unsigned short* __restrict__ partO, const float* __restrict__ partL,
    const unsigned short* __restrict__ Cmat, const float* __restrict__ cvec,
    float* __restrict__ out)
{
  __shared__ __align__(16) unsigned short plds[16*1024];
  __shared__ float s0s[64], s1s[64];
  const int tid = threadIdx.x;
  const int g = blockIdx.x >> 1, qh = blockIdx.x & 1;
  const int p0 = 2*g, p1 = 2*g + 1;
  if (tid < 64){
    const int h = tid >> 4, qr = tid & 15;
    const int row = h*32 + qh*16 + qr;
    const float L0 = partL[p0*128 + row], L1 = partL[p1*128 + row];
    const float inv = 1.f / (L0 + L1);
    s0s[tid] = L0*inv; s1s[tid] = L1*inv;
  }
  __syncthreads();
  #pragma unroll
  for (int i = 0; i < 8; i++){
    const int idx = tid + i*512;
    const int qr = idx >> 8;            // 0..15
    const int cg = idx & 255;           // group of 4 cols
    const int h = cg >> 6, f4 = (cg & 63)*4;
    const int row = h*32 + qh*16 + qr;
    const uint2 a0 = *reinterpret_cast<const uint2*>(&partO[(size_t)(p0*128 + row)*256 + f4]);
    const uint2 a1 = *reinterpret_cast<const uint2*>(&partO[(size_t)(p1*128 + row)*256 + f4]);
    const float w0 = s0s[h*16 + qr], w1 = s1s[h*16 + qr];
    const float v0 = w0*__uint_as_float(a0.x << 16)          + w1*__uint_as_float(a1.x << 16);
    const float v1 = w0*__uint_as_float(a0.x & 0xffff0000u)  + w1*__uint_as_float(a1.x & 0xffff0000u);
    const float v2 = w0*__uint_as_float(a0.y << 16)          + w1*__uint_as_float(a1.y << 16);
    const float v3 = w0*__uint_as_float(a0.y & 0xffff0000u)  + w1*__uint_as_float(a1.y & 0xffff0000u);
    uint2 w; w.x = cvtpk(v0, v1); w.y = cvtpk(v2, v3);
    const int bc = (cg*8) ^ ((qr & 7) << 4);   // col4 = cg*4, byte = col4*2
    *reinterpret_cast<uint2*>(reinterpret_cast<char*>(plds) + qr*2048 + bc) = w;
  }
  __syncthreads();
  const int wave = tid >> 6, lane = tid & 63, lg = lane >> 4, li = lane & 15;
  f32x4 acc0 = {0.f,0.f,0.f,0.f}, acc1 = {0.f,0.f,0.f,0.f};
  const float cv0 = cvec[wave*32 + li], cv1 = cvec[wave*32 + 16 + li];
  const unsigned short* cb0 = Cmat + (size_t)(wave*32 + li)*1024;
  const unsigned short* cb1 = Cmat + (size_t)(wave*32 + 16 + li)*1024;
  #pragma unroll 8
  for (int kb = 0; kb < 32; kb++){
    const int bc = ((kb*32 + lg*8)*2) ^ ((li & 7) << 4);
    const bf16x8 aa = *reinterpret_cast<const bf16x8*>(reinterpret_cast<const char*>(plds) + li*2048 + bc);
    const bf16x8 b0 = *reinterpret_cast<const bf16x8*>(cb0 + kb*32 + lg*8);
    const bf16x8 b1 = *reinterpret_cast<const bf16x8*>(cb1 + kb*32 + lg*8);
    acc0 = MFMA16(aa, b0, acc0);
    acc1 = MFMA16(aa, b1, acc1);
  }
  #pragma unroll
  for (int r = 0; r < 4; r++){
    const int q = lg*4 + r;
    const size_t orow = (size_t)(g*32 + qh*16 + q)*256;
    out[orow + wave*32 + li]      = acc0[r] + cv0;
    out[orow + wave*32 + 16 + li] = acc1[r] + cv1;
  }
}

// ---------------- launch ----------------

extern "C" void kernel_launch(void* const* d_in, const int* in_sizes, int n_in,
                              void* d_out, int out_size, void* d_ws, size_t ws_size,
                              hipStream_t stream)
{
  const float* x       = (const float*)d_in[0];
  const int*   batch   = (const int*)d_in[1];
  const float* queries = (const float*)d_in[2];
  const float* ipw     = (const float*)d_in[3];
  const float* ipb     = (const float*)d_in[4];
  const float* opw     = (const float*)d_in[5];
  const float* opb     = (const float*)d_in[6];
  float* out = (float*)d_out;
  const int total = in_sizes[1];

  char* w = (char*)d_ws;
  int*            starts = (int*)(w);
  unsigned short* AqF    = (unsigned short*)(w + 36*1024);
  unsigned short* Cmat   = (unsigned short*)(w + 102*1024);
  float*          cvec   = (float*)(w + 616*1024);
  unsigned short* partO  = (unsigned short*)(w + (size_t)1024*1024);
  float*          partL  = (float*)(w + (size_t)1024*1024 + (size_t)256*128*256*2);

  k_prep<<<544, 256, 0, stream>>>(queries, ipw, ipb, opw, opb, batch, total,
                                  starts, AqF, Cmat, cvec);
  k_attn<<<256, 1024, 0, stream>>>(x, starts, AqF, partO, partL);
  k_out<<<256, 512, 0, stream>>>(partO, partL, Cmat, cvec, out);
}

// Round 15
// 93.045 us; speedup vs baseline: 1.3582x; 1.3582x over previous
//
#include <hip/hip_runtime.h>
#include <hip/hip_bf16.h>

typedef __bf16 bf16x8 __attribute__((ext_vector_type(8)));
typedef float  f32x4  __attribute__((ext_vector_type(4)));

#define MFMA16(a,b,c) __builtin_amdgcn_mfma_f32_16x16x32_bf16((a),(b),(c),0,0,0)

__device__ __forceinline__ unsigned short f2bf(float f){
  unsigned int u = __float_as_uint(f);
  u += 0x7fffu + ((u >> 16) & 1u);
  return (unsigned short)(u >> 16);
}

// pack 2 f32 -> 2 bf16 in one instr (RTE)
__device__ __forceinline__ unsigned int cvtpk(float lo, float hi){
  unsigned int r;
  asm("v_cvt_pk_bf16_f32 %0, %1, %2" : "=v"(r) : "v"(lo), "v"(hi));
  return r;
}

// LDS-visibility sync WITHOUT vmcnt(0) drain (keeps global loads in flight)
__device__ __forceinline__ void block_sync(){
  asm volatile("s_waitcnt lgkmcnt(0)" ::: "memory");
  __builtin_amdgcn_s_barrier();
}

constexpr float SCALE_LOG2E = 0.125f * 1.4426950408889634f; // 1/sqrt(64) * log2(e)

// ---------------- merged prep kernel ----------------
// blocks 0..31: qs + AqT fragments ; 32..287: Cmat+cvec ; 288..543: starts scan
__global__ void k_prep(const float* __restrict__ queries, const float* __restrict__ ipw,
                       const float* __restrict__ ipb, const float* __restrict__ opw,
                       const float* __restrict__ opb, const int* __restrict__ batch,
                       int total, int* __restrict__ starts,
                       unsigned short* __restrict__ AqF,
                       unsigned short* __restrict__ Cmat, float* __restrict__ cvec)
{
  __shared__ __align__(16) float sh[256];
  __shared__ __align__(16) float sh2[256];
  const int t = threadIdx.x, bid = blockIdx.x;

  if (bid < 32){
    const int q = bid;
    sh[t] = queries[q*256 + t];
    __syncthreads();
    const float* wr = ipw + (size_t)t*256;
    float acc = 0.f;
    #pragma unroll 8
    for (int j = 0; j < 256; j += 4){
      float4 wv = *reinterpret_cast<const float4*>(wr + j);
      float4 qv = *reinterpret_cast<const float4*>(&sh[j]);
      acc += wv.x*qv.x + wv.y*qv.y + wv.z*qv.z + wv.w*qv.w;
    }
    sh2[t] = acc + ipb[t];
    __syncthreads();
    #pragma unroll
    for (int h = 0; h < 4; h++){
      const float* wk = ipw + (size_t)(256 + h*64)*256 + t;
      float a2 = 0.f;
      #pragma unroll 8
      for (int d = 0; d < 64; d++) a2 += sh2[h*64 + d] * wk[(size_t)d*256];
      // B-frag layout: AqF[rg=h*2+qh][kb=f>>5][lane=((f>>3)&3)*16 + (q&15)][j=f&7]
      const int dst = ((h*2 + (q>>4))*8 + (t>>5))*512 + (((t>>3)&3)*16 + (q&15))*8 + (t&7);
      AqF[dst] = f2bf(a2 * SCALE_LOG2E);
    }
  } else if (bid < 288){
    const int g = bid - 32;
    sh[t] = opw[(size_t)g*256 + t];
    __syncthreads();
    #pragma unroll
    for (int h = 0; h < 4; h++){
      const float* wv = ipw + (size_t)(512 + h*64)*256 + t;
      float acc = 0.f;
      #pragma unroll 8
      for (int d = 0; d < 64; d++) acc += wv[(size_t)d*256] * sh[h*64 + d];
      Cmat[(size_t)g*1024 + h*256 + t] = f2bf(acc);
    }
    sh2[t] = ipb[512 + t] * sh[t];
    __syncthreads();
    for (int off = 128; off > 0; off >>= 1){
      if (t < off) sh2[t] += sh2[t + off];
      __syncthreads();
    }
    if (t == 0) cvec[g] = sh2[0] + opb[g];
  } else {
    const int sb = bid - 288;
    const int i0 = sb*1024 + t*4;
    if (i0 + 3 < total){
      if (i0 == 0) starts[0] = 0;
      const int4 b4 = *reinterpret_cast<const int4*>(batch + i0);
      if (b4.y != b4.x) starts[b4.y] = i0 + 1;
      if (b4.z != b4.y) starts[b4.z] = i0 + 2;
      if (b4.w != b4.z) starts[b4.w] = i0 + 3;
      if (i0 + 4 < total){
        const int nxt = batch[i0 + 4];
        if (nxt != b4.w) starts[nxt] = i0 + 4;
      } else {
        starts[128] = total;
      }
    }
  }
}

// ---------------- fused attention over raw x (no-max softmax) ----------------
// grid 256 = graph*2 splits, 1024 threads (16 waves, 4 waves/SIMD).
// Compute specialization:
//  S-waves 0..7  (rg2 = w>>1, bsel = w&1): rows [rg2*32,+32) x nodes [bsel*16,+16).
//  PV-waves 8..15 (pw): 64 rows x 64 f tile, lagging one barrier interval behind S.
// Staging spread across ALL 16 waves: wave = 2 nodes, lane = f-quad (float4, 16B/lane).
// Schedule per iteration c:
//  S : S(c) MFMA -> STAGE(c+1) -> softmax+P-write(c) -> barrier   (stage overlaps exp2)
//  PV: STAGE(c+1) -> barrier -> PV(c)                             (PV(c) in interval c+1)
// Epilogue: PV waves write NORMALIZED bf16 partO (O_s/L_s); k_out recombines
// with weights w_s = L_s/(L0+L1). VGPR budget ~120/128 at 4 waves/SIMD — do NOT
// add register buffers (r14 lesson: +8 VGPR -> spill -> -32us).

#define LOADC(dst, c_) { \
  const int c0_ = (c_)*32; \
  _Pragma("unroll") \
  for (int n = 0; n < 2; n++){ \
    int nl_ = c0_ + np*2 + n; nl_ = nl_ < cnt-1 ? nl_ : cnt-1; \
    dst[n] = *reinterpret_cast<const float4*>(xg + (size_t)nl_*256 + fq*4); } }

// xsub [node][f] pad 264 ; xT [f][node] pad 40 + XOR swizzle
#define STAGE(xsP, xtP, src) { \
  _Pragma("unroll") \
  for (int n = 0; n < 2; n++){ \
    uint2 w_; w_.x = cvtpk(src[n].x, src[n].y); w_.y = cvtpk(src[n].z, src[n].w); \
    *reinterpret_cast<uint2*>(&(xsP)[(np*2 + n)*264 + fq*4]) = w_; \
  } \
  { const int fb_ = fq*4; \
    const unsigned int wx = cvtpk(src[0].x, src[1].x); \
    const unsigned int wy = cvtpk(src[0].y, src[1].y); \
    const unsigned int wz = cvtpk(src[0].z, src[1].z); \
    const unsigned int ww = cvtpk(src[0].w, src[1].w); \
    char* xb_ = reinterpret_cast<char*>(xtP); \
    *reinterpret_cast<unsigned int*>(xb_ + (((fb_+0)*80 + np*4) ^ ((((fb_+0)>>2)&7)<<4))) = wx; \
    *reinterpret_cast<unsigned int*>(xb_ + (((fb_+1)*80 + np*4) ^ ((((fb_+1)>>2)&7)<<4))) = wy; \
    *reinterpret_cast<unsigned int*>(xb_ + (((fb_+2)*80 + np*4) ^ ((((fb_+2)>>2)&7)<<4))) = wz; \
    *reinterpret_cast<unsigned int*>(xb_ + (((fb_+3)*80 + np*4) ^ ((((fb_+3)>>2)&7)<<4))) = ww; \
  } }

__global__ __launch_bounds__(1024, 4) void k_attn(
    const float* __restrict__ x, const int* __restrict__ starts,
    const unsigned short* __restrict__ AqF,
    unsigned short* __restrict__ partO, float* __restrict__ partL)
{
  __shared__ __align__(16) unsigned short xsub[2][32*264];
  __shared__ __align__(16) unsigned short xT  [3][256*40];
  __shared__ __align__(16) unsigned short Plds[2][128*40];
  __shared__ __align__(16) float lred[2][128];

  const int tid = threadIdx.x;
  const int wave = tid >> 6, lane = tid & 63, lg = lane >> 4, li = lane & 15;
  const int np = wave, fq = lane;              // stage role: 2 nodes per wave, f-quad per lane
  const int bid = blockIdx.x;
  const int g = bid >> 1, s = bid & 1;
  const int s0 = starts[g], s1 = starts[g+1];
  const int cntg = s1 - s0;
  const int half = (cntg + 1) >> 1;
  const int nstart = s0 + s*half;
  int cnt = cntg - s*half; cnt = cnt < 0 ? 0 : (cnt > half ? half : cnt);
  const int chunks = (cnt + 31) >> 5;
  const float* xg = x + (size_t)nstart*256;
  const int pbase = bid*128;

  float4 rA[2];
  if (chunks > 0){
    LOADC(rA, 0);
    STAGE(xsub[0], xT[0], rA);
    if (chunks > 1) LOADC(rA, 1);
  }
  block_sync();   // B0

  // PV tile bases (used in epilogue too)
  const int pw = wave - 8;
  const int rbase = (pw & 1) * 64;
  const int fbase = (pw >> 1) * 64;
  f32x4 oacc[4][4];  // PV accumulators
  #pragma unroll
  for (int i = 0; i < 4; i++)
    #pragma unroll
    for (int j = 0; j < 4; j++) oacc[i][j] = f32x4{0.f,0.f,0.f,0.f};

  if (wave < 8){
    // ================= S-waves =================
    const int rg2 = wave >> 1, bsel = wave & 1;
    bf16x8 bfragS[2][8];
    #pragma unroll
    for (int rf = 0; rf < 2; rf++)
      #pragma unroll
      for (int kb = 0; kb < 8; kb++)
        bfragS[rf][kb] = *reinterpret_cast<const bf16x8*>(AqF + (size_t)((rg2*2 + rf)*8 + kb)*512 + lane*8);

    float rsum0 = 0.f, rsum1 = 0.f;
    const int row0 = rg2*32 + li, row1 = rg2*32 + 16 + li;
    const int pbyte0 = (row0*80 + bsel*32 + lg*8) ^ (((row0>>2)&7)<<4);
    const int pbyte1 = (row1*80 + bsel*32 + lg*8) ^ (((row1>>2)&7)<<4);

    int wr3 = 1;
    for (int c = 0; c < chunks; ++c){
      const int cur2 = c & 1;

      // ---- S(c): batched fragment reads + 16 MFMA ----
      f32x4 sc0 = f32x4{0.f,0.f,0.f,0.f}, sc1 = f32x4{0.f,0.f,0.f,0.f};
      const unsigned short* xs = &xsub[cur2][(bsel*16 + li)*264 + lg*8];
      bf16x8 af[4];
      __builtin_amdgcn_s_setprio(1);
      #pragma unroll
      for (int kb = 0; kb < 4; kb++) af[kb] = *reinterpret_cast<const bf16x8*>(xs + kb*32);
      #pragma unroll
      for (int kb = 0; kb < 4; kb++){
        sc0 = MFMA16(af[kb], bfragS[0][kb], sc0);
        sc1 = MFMA16(af[kb], bfragS[1][kb], sc1);
      }
      #pragma unroll
      for (int kb = 0; kb < 4; kb++) af[kb] = *reinterpret_cast<const bf16x8*>(xs + (4+kb)*32);
      #pragma unroll
      for (int kb = 0; kb < 4; kb++){
        sc0 = MFMA16(af[kb], bfragS[0][4+kb], sc0);
        sc1 = MFMA16(af[kb], bfragS[1][4+kb], sc1);
      }
      __builtin_amdgcn_s_setprio(0);

      // ---- stage chunk c+1 FIRST (independent of softmax); overlaps exp2 chain ----
      if (c + 1 < chunks){
        STAGE(xsub[(c + 1) & 1], xT[wr3], rA);
        if (c + 2 < chunks) LOADC(rA, c + 2);
      }

      // ---- P = exp2(S), masked; P-write ----
      const int nodebase = c*32 + bsel*16 + lg*4;
      float p0[4], p1[4];
      #pragma unroll
      for (int r = 0; r < 4; r++){
        const bool v = (nodebase + r) < cnt;
        p0[r] = v ? __builtin_exp2f(sc0[r]) : 0.f;
        p1[r] = v ? __builtin_exp2f(sc1[r]) : 0.f;
        rsum0 += p0[r]; rsum1 += p1[r];
      }
      {
        char* pl = reinterpret_cast<char*>(Plds[cur2]);
        uint2 w0; w0.x = cvtpk(p0[0], p0[1]); w0.y = cvtpk(p0[2], p0[3]);
        uint2 w1; w1.x = cvtpk(p1[0], p1[1]); w1.y = cvtpk(p1[2], p1[3]);
        *reinterpret_cast<uint2*>(pl + pbyte0) = w0;
        *reinterpret_cast<uint2*>(pl + pbyte1) = w1;
      }

      block_sync();   // B_{c+1}
      wr3 = (wr3 == 2) ? 0 : wr3 + 1;
    }

    rsum0 += __shfl_xor(rsum0, 16); rsum0 += __shfl_xor(rsum0, 32);
    rsum1 += __shfl_xor(rsum1, 16); rsum1 += __shfl_xor(rsum1, 32);
    if (lane < 16){
      lred[bsel][rg2*32 + li]      = rsum0;
      lred[bsel][rg2*32 + 16 + li] = rsum1;
    }
  } else {
    // ================= PV-waves =================
    int bvb[4], pab[4];
    #pragma unroll
    for (int t4 = 0; t4 < 4; t4++){
      const int fr = fbase + t4*16 + li;
      bvb[t4] = (fr*80 + lg*16) ^ (((fr>>2)&7)<<4);
      const int pr = rbase + t4*16 + li;
      pab[t4] = (pr*80 + lg*16) ^ (((pr>>2)&7)<<4);
    }

    int cur3 = 0;
    for (int c = 0; c < chunks; ++c){
      const int cur2 = c & 1;
      const int nxt3 = (cur3 == 2) ? 0 : cur3 + 1;

      // ---- stage chunk c+1, refill regs with c+2 ----
      if (c + 1 < chunks){
        STAGE(xsub[(c + 1) & 1], xT[nxt3], rA);
        if (c + 2 < chunks) LOADC(rA, c + 2);
      }
      block_sync();   // B_{c+1}

      // ---- PV(c): batched reads, then pure MFMA cluster ----
      const char* xtC = reinterpret_cast<const char*>(xT[cur3]);
      const char* plC = reinterpret_cast<const char*>(Plds[cur2]);
      bf16x8 bv[4], pa[4];
      #pragma unroll
      for (int ft = 0; ft < 4; ft++)
        bv[ft] = *reinterpret_cast<const bf16x8*>(xtC + bvb[ft]);
      #pragma unroll
      for (int rt = 0; rt < 4; rt++)
        pa[rt] = *reinterpret_cast<const bf16x8*>(plC + pab[rt]);
      __builtin_amdgcn_s_setprio(1);
      #pragma unroll
      for (int rt = 0; rt < 4; rt++){
        #pragma unroll
        for (int ft = 0; ft < 4; ft++)
          oacc[rt][ft] = MFMA16(pa[rt], bv[ft], oacc[rt][ft]);
      }
      __builtin_amdgcn_s_setprio(0);
      cur3 = nxt3;
    }
  }

  block_sync();   // final: lred visible to all waves

  if (wave >= 8){
    // ---- epilogue: normalize by this block's L_s and store bf16 ----
    #pragma unroll
    for (int rt = 0; rt < 4; rt++){
      const int r0 = rbase + rt*16 + lg*4;
      const f32x4 L0v = *reinterpret_cast<const f32x4*>(&lred[0][r0]);
      const f32x4 L1v = *reinterpret_cast<const f32x4*>(&lred[1][r0]);
      #pragma unroll
      for (int r = 0; r < 4; r++){
        const float L = L0v[r] + L1v[r];
        const float inv = (L > 0.f) ? 1.f/L : 0.f;
        const size_t orow = (size_t)(pbase + r0 + r)*256;
        #pragma unroll
        for (int ft = 0; ft < 4; ft++)
          partO[orow + fbase + ft*16 + li] = f2bf(oacc[rt][ft][r]*inv);
      }
    }
  }
  if (tid < 128) partL[pbase + tid] = lred[0][tid] + lred[1][tid];
}

// ---------------- combine normalized partials + out-proj GEMM ----------------
__global__ __launch_bounds__(512, 1) void k_out(
    const unsigned short* __restrict__ partO, const float* __restrict__ partL,
    const unsigned short* __restrict__ Cmat, const float* __restrict__ cvec,
    float* __restrict__ out)
{
  __shared__ __align__(16) unsigned short plds[16*1024];
  __shared__ float s0s[64], s1s[64];
  const int tid = threadIdx.x;
  const int g = blockIdx.x >> 1, qh = blockIdx.x & 1;
  const int p0 = 2*g, p1 = 2*g + 1;
  if (tid < 64){
    const int h = tid >> 4, qr = tid & 15;
    const int row = h*32 + qh*16 + qr;
    const float L0 = partL[p0*128 + row], L1 = partL[p1*128 + row];
    const float inv = 1.f / (L0 + L1);
    s0s[tid] = L0*inv; s1s[tid] = L1*inv;
  }
  __syncthreads();
  #pragma unroll
  for (int i = 0; i < 8; i++){
    const int idx = tid + i*512;
    const int qr = idx >> 8;            // 0..15
    const int cg = idx & 255;           // group of 4 cols
    const int h = cg >> 6, f4 = (cg & 63)*4;
    const int row = h*32 + qh*16 + qr;
    const uint2 a0 = *reinterpret_cast<const uint2*>(&partO[(size_t)(p0*128 + row)*256 + f4]);
    const uint2 a1 = *reinterpret_cast<const uint2*>(&partO[(size_t)(p1*128 + row)*256 + f4]);
    const float w0 = s0s[h*16 + qr], w1 = s1s[h*16 + qr];
    const float v0 = w0*__uint_as_float(a0.x << 16)          + w1*__uint_as_float(a1.x << 16);
    const float v1 = w0*__uint_as_float(a0.x & 0xffff0000u)  + w1*__uint_as_float(a1.x & 0xffff0000u);
    const float v2 = w0*__uint_as_float(a0.y << 16)          + w1*__uint_as_float(a1.y << 16);
    const float v3 = w0*__uint_as_float(a0.y & 0xffff0000u)  + w1*__uint_as_float(a1.y & 0xffff0000u);
    uint2 w; w.x = cvtpk(v0, v1); w.y = cvtpk(v2, v3);
    const int bc = (cg*8) ^ ((qr & 7) << 4);   // col4 = cg*4, byte = col4*2
    *reinterpret_cast<uint2*>(reinterpret_cast<char*>(plds) + qr*2048 + bc) = w;
  }
  __syncthreads();
  const int wave = tid >> 6, lane = tid & 63, lg = lane >> 4, li = lane & 15;
  f32x4 acc0 = {0.f,0.f,0.f,0.f}, acc1 = {0.f,0.f,0.f,0.f};
  const float cv0 = cvec[wave*32 + li], cv1 = cvec[wave*32 + 16 + li];
  const unsigned short* cb0 = Cmat + (size_t)(wave*32 + li)*1024;
  const unsigned short* cb1 = Cmat + (size_t)(wave*32 + 16 + li)*1024;
  #pragma unroll 8
  for (int kb = 0; kb < 32; kb++){
    const int bc = ((kb*32 + lg*8)*2) ^ ((li & 7) << 4);
    const bf16x8 aa = *reinterpret_cast<const bf16x8*>(reinterpret_cast<const char*>(plds) + li*2048 + bc);
    const bf16x8 b0 = *reinterpret_cast<const bf16x8*>(cb0 + kb*32 + lg*8);
    const bf16x8 b1 = *reinterpret_cast<const bf16x8*>(cb1 + kb*32 + lg*8);
    acc0 = MFMA16(aa, b0, acc0);
    acc1 = MFMA16(aa, b1, acc1);
  }
  #pragma unroll
  for (int r = 0; r < 4; r++){
    const int q = lg*4 + r;
    const size_t orow = (size_t)(g*32 + qh*16 + q)*256;
    out[orow + wave*32 + li]      = acc0[r] + cv0;
    out[orow + wave*32 + 16 + li] = acc1[r] + cv1;
  }
}

// ---------------- launch ----------------

extern "C" void kernel_launch(void* const* d_in, const int* in_sizes, int n_in,
                              void* d_out, int out_size, void* d_ws, size_t ws_size,
                              hipStream_t stream)
{
  const float* x       = (const float*)d_in[0];
  const int*   batch   = (const int*)d_in[1];
  const float* queries = (const float*)d_in[2];
  const float* ipw     = (const float*)d_in[3];
  const float* ipb     = (const float*)d_in[4];
  const float* opw     = (const float*)d_in[5];
  const float* opb     = (const float*)d_in[6];
  float* out = (float*)d_out;
  const int total = in_sizes[1];

  char* w = (char*)d_ws;
  int*            starts = (int*)(w);
  unsigned short* AqF    = (unsigned short*)(w + 36*1024);
  unsigned short* Cmat   = (unsigned short*)(w + 102*1024);
  float*          cvec   = (float*)(w + 616*1024);
  unsigned short* partO  = (unsigned short*)(w + (size_t)1024*1024);
  float*          partL  = (float*)(w + (size_t)1024*1024 + (size_t)256*128*256*2);

  k_prep<<<544, 256, 0, stream>>>(queries, ipw, ipb, opw, opb, batch, total,
                                  starts, AqF, Cmat, cvec);
  k_attn<<<256, 1024, 0, stream>>>(x, starts, AqF, partO, partL);
  k_out<<<256, 512, 0, stream>>>(partO, partL, Cmat, cvec, out);
}